// Round 1
// baseline (1059.071 us; speedup 1.0000x reference)
//
#include <hip/hip_runtime.h>
#include <stdint.h>

// Problem constants (match reference)
#define NB       64    // nodes per graph
#define FIN      12    // input features
#define HD       64    // hidden dim
#define NHEADS   4
#define DHEAD    16
#define NLAYERS  3
#define ODIM     128
#define LN_EPS   1e-5f
#define BTOT     8192

#define LDH      68    // padded LDS row stride (floats); 68%4==0 keeps float4 aligned,
                       // 68 floats -> bank shift 4 per row -> <=2-way conflicts (free)
#define NTHREADS 512   // 2 batch elements x 256 threads

struct __align__(16) Smem {
  float H[2][NB * LDH];           // residual stream h
  float Q[2][NB * LDH];           // q, later attention output o
  float K[2][NB * LDH];           // x staging (stride 16), k, later pre-LN u
  float V[2][NB * LDH];           // v
  float W[HD * HD];               // shared weight staging (both halves)
  unsigned long long mask[NB];    // adjacency bitmask per row (shared)
  float pool[2][HD];
  float y1[2][HD];
};                                 // 157184 B total (<160 KiB)

// acc += A[r0..r0+3][0..63] (stride LDH) @ W[0..63][c0..c0+3] (stride 64)
__device__ __forceinline__ void gemm_tile64(const float* __restrict__ A,
                                            const float* __restrict__ Wm,
                                            int r0, int c0, float acc[4][4]) {
  #pragma unroll 4
  for (int kk = 0; kk < HD; kk += 4) {
    float a[4][4], b[4][4];
    #pragma unroll
    for (int ii = 0; ii < 4; ++ii) {
      const float4 v4 = *(const float4*)&A[(r0 + ii) * LDH + kk];
      a[ii][0] = v4.x; a[ii][1] = v4.y; a[ii][2] = v4.z; a[ii][3] = v4.w;
    }
    #pragma unroll
    for (int kt = 0; kt < 4; ++kt) {
      const float4 v4 = *(const float4*)&Wm[(kk + kt) * HD + c0];
      b[kt][0] = v4.x; b[kt][1] = v4.y; b[kt][2] = v4.z; b[kt][3] = v4.w;
    }
    #pragma unroll
    for (int ii = 0; ii < 4; ++ii)
      #pragma unroll
      for (int kt = 0; kt < 4; ++kt)
        #pragma unroll
        for (int jj = 0; jj < 4; ++jj)
          acc[ii][jj] = fmaf(a[ii][kt], b[kt][jj], acc[ii][jj]);
  }
}

__device__ __forceinline__ void load_w64(float* __restrict__ dst,
                                         const float* __restrict__ src, int tid) {
  // 64x64 floats = 1024 float4s, 512 threads -> 2 each, coalesced
  for (int j = tid; j < (HD * HD) / 4; j += NTHREADS)
    ((float4*)dst)[j] = ((const float4*)src)[j];
}

extern "C" __global__ void __launch_bounds__(NTHREADS)
gnn_fused(const float* __restrict__ x, const int* __restrict__ adj,
          const float* __restrict__ W_in, const float* __restrict__ b_in,
          const float* __restrict__ Wq, const float* __restrict__ Wk,
          const float* __restrict__ Wv, const float* __restrict__ Wo,
          const float* __restrict__ bo, const float* __restrict__ ln_g,
          const float* __restrict__ ln_b, const float* __restrict__ Wp1,
          const float* __restrict__ bp1, const float* __restrict__ Wp2,
          const float* __restrict__ bp2, float* __restrict__ out) {
  __shared__ Smem s;
  const int tid = threadIdx.x;
  const int be  = tid >> 8;          // which of the 2 batch elements
  const int t   = tid & 255;         // thread id within the element
  const int eg  = (int)blockIdx.x * 2 + be;

  float* __restrict__ sH = s.H[be];
  float* __restrict__ sQ = s.Q[be];
  float* __restrict__ sK = s.K[be];
  float* __restrict__ sV = s.V[be];

  const int tr = t >> 4, tc = t & 15;
  const int r0 = tr * 4, c0 = tc * 4;

  // ---------- phase 0: stage x (into sK region, row stride 16), W_in, zero mask
  for (int j = t; j < NB * FIN; j += 256) {
    const int i = j / FIN, f = j - i * FIN;
    sK[i * 16 + f] = x[eg * (NB * FIN) + j];
  }
  for (int j = tid; j < FIN * HD; j += NTHREADS) s.W[j] = W_in[j];
  if (tid < NB) s.mask[tid] = 0ull;
  __syncthreads();

  // ---------- adjacency bitmask (once per block; shared by both halves)
  {
    const int mi = tid >> 3, jq = tid & 7;
    unsigned long long mm = 0ull;
    #pragma unroll
    for (int jj = 0; jj < 8; ++jj) {
      const int j = jq * 8 + jj;
      if (adj[mi * NB + j] != 0) mm |= (1ull << j);
    }
    atomicOr(&s.mask[mi], mm);
  }

  // ---------- h = x @ W_in + b_in
  {
    float acc[4][4] = {};
    #pragma unroll
    for (int kk = 0; kk < FIN; kk += 4) {
      float a[4][4], b[4][4];
      #pragma unroll
      for (int ii = 0; ii < 4; ++ii) {
        const float4 v4 = *(const float4*)&sK[(r0 + ii) * 16 + kk];
        a[ii][0] = v4.x; a[ii][1] = v4.y; a[ii][2] = v4.z; a[ii][3] = v4.w;
      }
      #pragma unroll
      for (int kt = 0; kt < 4; ++kt) {
        const float4 v4 = *(const float4*)&s.W[(kk + kt) * HD + c0];
        b[kt][0] = v4.x; b[kt][1] = v4.y; b[kt][2] = v4.z; b[kt][3] = v4.w;
      }
      #pragma unroll
      for (int ii = 0; ii < 4; ++ii)
        #pragma unroll
        for (int kt = 0; kt < 4; ++kt)
          #pragma unroll
          for (int jj = 0; jj < 4; ++jj)
            acc[ii][jj] = fmaf(a[ii][kt], b[kt][jj], acc[ii][jj]);
    }
    const float4 bv = *(const float4*)&b_in[c0];
    const float bb[4] = {bv.x, bv.y, bv.z, bv.w};
    #pragma unroll
    for (int ii = 0; ii < 4; ++ii) {
      float4 o4;
      o4.x = acc[ii][0] + bb[0]; o4.y = acc[ii][1] + bb[1];
      o4.z = acc[ii][2] + bb[2]; o4.w = acc[ii][3] + bb[3];
      *(float4*)&sH[(r0 + ii) * LDH + c0] = o4;
    }
  }
  __syncthreads();

  // ---------- transformer layers
  for (int l = 0; l < NLAYERS; ++l) {
    const float* wq = Wq + l * HD * HD;
    const float* wk = Wk + l * HD * HD;
    const float* wv = Wv + l * HD * HD;
    const float* wo = Wo + l * HD * HD;

    // q = h @ Wq
    load_w64(s.W, wq, tid); __syncthreads();
    {
      float acc[4][4] = {};
      gemm_tile64(sH, s.W, r0, c0, acc);
      #pragma unroll
      for (int ii = 0; ii < 4; ++ii) {
        float4 o4 = {acc[ii][0], acc[ii][1], acc[ii][2], acc[ii][3]};
        *(float4*)&sQ[(r0 + ii) * LDH + c0] = o4;
      }
    }
    __syncthreads();

    // k = h @ Wk
    load_w64(s.W, wk, tid); __syncthreads();
    {
      float acc[4][4] = {};
      gemm_tile64(sH, s.W, r0, c0, acc);
      #pragma unroll
      for (int ii = 0; ii < 4; ++ii) {
        float4 o4 = {acc[ii][0], acc[ii][1], acc[ii][2], acc[ii][3]};
        *(float4*)&sK[(r0 + ii) * LDH + c0] = o4;
      }
    }
    __syncthreads();

    // v = h @ Wv
    load_w64(s.W, wv, tid); __syncthreads();
    {
      float acc[4][4] = {};
      gemm_tile64(sH, s.W, r0, c0, acc);
      #pragma unroll
      for (int ii = 0; ii < 4; ++ii) {
        float4 o4 = {acc[ii][0], acc[ii][1], acc[ii][2], acc[ii][3]};
        *(float4*)&sV[(r0 + ii) * LDH + c0] = o4;
      }
    }
    __syncthreads();

    // masked attention, online softmax over set bits only (<=9 neighbors/row).
    // thread (head hh, row i); q segment is private to this thread, o overwrites it.
    {
      const int hh = t >> 6;
      const int i  = t & 63;
      const float* qp = &sQ[i * LDH + hh * DHEAD];
      float qv[DHEAD];
      #pragma unroll
      for (int c = 0; c < DHEAD; c += 4) {
        const float4 v4 = *(const float4*)&qp[c];
        qv[c] = v4.x; qv[c + 1] = v4.y; qv[c + 2] = v4.z; qv[c + 3] = v4.w;
      }
      unsigned long long m = s.mask[i];
      float mx = -1e30f, sum = 0.0f;
      float o[DHEAD];
      #pragma unroll
      for (int c = 0; c < DHEAD; ++c) o[c] = 0.0f;

      while (m) {
        const int j = __builtin_ctzll(m);
        m &= (m - 1);
        const float* kp = &sK[j * LDH + hh * DHEAD];
        float sc = 0.0f;
        #pragma unroll
        for (int c = 0; c < DHEAD; c += 4) {
          const float4 k4 = *(const float4*)&kp[c];
          sc = fmaf(qv[c], k4.x, sc);     sc = fmaf(qv[c + 1], k4.y, sc);
          sc = fmaf(qv[c + 2], k4.z, sc); sc = fmaf(qv[c + 3], k4.w, sc);
        }
        sc *= 0.25f;  // 1/sqrt(16)
        const float mnew  = fmaxf(mx, sc);
        const float alpha = __expf(mx - mnew);
        const float p     = __expf(sc - mnew);
        mx = mnew;
        sum = sum * alpha + p;
        const float* vp = &sV[j * LDH + hh * DHEAD];
        #pragma unroll
        for (int c = 0; c < DHEAD; c += 4) {
          const float4 v4 = *(const float4*)&vp[c];
          o[c]     = o[c]     * alpha + p * v4.x;
          o[c + 1] = o[c + 1] * alpha + p * v4.y;
          o[c + 2] = o[c + 2] * alpha + p * v4.z;
          o[c + 3] = o[c + 3] * alpha + p * v4.w;
        }
      }
      const float rinv = 1.0f / sum;
      float* op = &sQ[i * LDH + hh * DHEAD];
      #pragma unroll
      for (int c = 0; c < DHEAD; c += 4) {
        float4 o4;
        o4.x = o[c] * rinv; o4.y = o[c + 1] * rinv;
        o4.z = o[c + 2] * rinv; o4.w = o[c + 3] * rinv;
        *(float4*)&op[c] = o4;
      }
    }
    __syncthreads();

    // u = h + o @ Wo + bo   -> sK
    load_w64(s.W, wo, tid); __syncthreads();
    {
      float acc[4][4] = {};
      gemm_tile64(sQ, s.W, r0, c0, acc);
      const float4 bv = *(const float4*)&bo[l * HD + c0];
      const float bb[4] = {bv.x, bv.y, bv.z, bv.w};
      #pragma unroll
      for (int ii = 0; ii < 4; ++ii) {
        const float4 h4 = *(const float4*)&sH[(r0 + ii) * LDH + c0];
        float4 o4;
        o4.x = acc[ii][0] + h4.x + bb[0];
        o4.y = acc[ii][1] + h4.y + bb[1];
        o4.z = acc[ii][2] + h4.z + bb[2];
        o4.w = acc[ii][3] + h4.w + bb[3];
        *(float4*)&sK[(r0 + ii) * LDH + c0] = o4;
      }
    }
    __syncthreads();

    // h = LayerNorm(u) * g + b   (4 lanes per row, shfl reduce)
    {
      const int i = t >> 2, q4 = t & 3;
      const float* up = &sK[i * LDH + q4 * 16];
      float uv[16];
      #pragma unroll
      for (int c = 0; c < 16; c += 4) {
        const float4 v4 = *(const float4*)&up[c];
        uv[c] = v4.x; uv[c + 1] = v4.y; uv[c + 2] = v4.z; uv[c + 3] = v4.w;
      }
      float s1 = 0.0f, s2 = 0.0f;
      #pragma unroll
      for (int c = 0; c < 16; ++c) { s1 += uv[c]; s2 += uv[c] * uv[c]; }
      s1 += __shfl_xor(s1, 1, 64); s1 += __shfl_xor(s1, 2, 64);
      s2 += __shfl_xor(s2, 1, 64); s2 += __shfl_xor(s2, 2, 64);
      const float mu  = s1 * (1.0f / 64.0f);
      const float var = s2 * (1.0f / 64.0f) - mu * mu;
      const float rs  = rsqrtf(var + LN_EPS);
      const float* gg = ln_g + l * HD + q4 * 16;
      const float* bb = ln_b + l * HD + q4 * 16;
      float* hp = &sH[i * LDH + q4 * 16];
      #pragma unroll
      for (int c = 0; c < 16; c += 4) {
        const float4 g4 = *(const float4*)&gg[c];
        const float4 b4 = *(const float4*)&bb[c];
        float4 o4;
        o4.x = (uv[c] - mu) * rs * g4.x + b4.x;
        o4.y = (uv[c + 1] - mu) * rs * g4.y + b4.y;
        o4.z = (uv[c + 2] - mu) * rs * g4.z + b4.z;
        o4.w = (uv[c + 3] - mu) * rs * g4.w + b4.w;
        *(float4*)&hp[c] = o4;
      }
    }
    __syncthreads();
  }

  // ---------- head: pooled mean -> relu(pooled@Wp1+bp1) -> @Wp2+bp2
  if (t < HD) {
    float sum = 0.0f;
    #pragma unroll 8
    for (int i = 0; i < NB; ++i) sum += sH[i * LDH + t];
    s.pool[be][t] = sum * (1.0f / 64.0f);
  }
  __syncthreads();
  if (t < HD) {
    float acc = bp1[t];
    #pragma unroll 8
    for (int k = 0; k < HD; ++k) acc = fmaf(s.pool[be][k], Wp1[k * HD + t], acc);
    s.y1[be][t] = fmaxf(acc, 0.0f);
  }
  __syncthreads();
  if (t < ODIM) {
    float acc = bp2[t];
    #pragma unroll 8
    for (int c = 0; c < HD; ++c) acc = fmaf(s.y1[be][c], Wp2[c * ODIM + t], acc);
    out[eg * ODIM + t] = acc;
  }
}

extern "C" void kernel_launch(void* const* d_in, const int* in_sizes, int n_in,
                              void* d_out, int out_size, void* d_ws, size_t ws_size,
                              hipStream_t stream) {
  const float* x    = (const float*)d_in[0];
  const int*   adj  = (const int*)d_in[1];
  const float* W_in = (const float*)d_in[2];
  const float* b_in = (const float*)d_in[3];
  const float* Wq   = (const float*)d_in[4];
  const float* Wk   = (const float*)d_in[5];
  const float* Wv   = (const float*)d_in[6];
  const float* Wo   = (const float*)d_in[7];
  const float* bo   = (const float*)d_in[8];
  const float* lng  = (const float*)d_in[9];
  const float* lnb  = (const float*)d_in[10];
  const float* Wp1  = (const float*)d_in[11];
  const float* bp1  = (const float*)d_in[12];
  const float* Wp2  = (const float*)d_in[13];
  const float* bp2  = (const float*)d_in[14];
  float* outp = (float*)d_out;

  dim3 grid(BTOT / 2), block(NTHREADS);
  hipLaunchKernelGGL(gnn_fused, grid, block, 0, stream,
                     x, adj, W_in, b_in, Wq, Wk, Wv, Wo, bo, lng, lnb,
                     Wp1, bp1, Wp2, bp2, outp);
}

// Round 2
// 490.590 us; speedup vs baseline: 2.1588x; 2.1588x over previous
//
#include <hip/hip_runtime.h>
#include <stdint.h>

// Problem constants
#define NB       64
#define FIN      12
#define HD       64
#define NHEADS   4
#define DHEAD    16
#define NLAYERS  3
#define ODIM     128
#define LN_EPS   1e-5f
#define BTOT     8192

#define LDF      68    // fp32 tile row stride (floats)
#define LDB      72    // bf16 tile row stride (elems); 144 B rows, 16B-aligned
#define NTH      256   // 4 waves, one batch element per block

typedef unsigned int       u32;
typedef unsigned short     u16;
typedef unsigned long long u64;

typedef __bf16 bf16x8 __attribute__((ext_vector_type(8)));
typedef float  f32x4  __attribute__((ext_vector_type(4)));
union U128 { uint4 u; bf16x8 b; };

struct __align__(16) Smem {
  float H [NB * LDF];   // 17408  residual h (fp32); u in-place pre-LN
  float Kf[NB * LDF];   // 17408  k fp32 (x staging in phase 0)
  float Vf[NB * LDF];   // 17408  v fp32
  u16   Hb[NB * LDB];   //  9216  h bf16, MFMA A-layout source
  u16   Qb[NB * LDB];   //  9216  q bf16, then attention output o
  u16   Wt[HD * LDB];   //  9216  staged weight, bf16, transposed (n-major)
  u64   mask[NB];       //   512  adjacency bitmasks
  float pool[HD];       //   256
  float y1[HD];         //   256
};                      // total 80896 B -> 2 blocks/CU

// fp32 -> bf16 RNE (finite inputs only)
__device__ __forceinline__ u16 f2b(float f) {
  u32 u = __float_as_uint(f);
  return (u16)((u + 0x7FFFu + ((u >> 16) & 1u)) >> 16);
}
__device__ __forceinline__ u32 f2b2(float lo, float hi) {
  return (u32)f2b(lo) | ((u32)f2b(hi) << 16);
}
__device__ __forceinline__ float b2f_lo(u32 u) { return __uint_as_float(u << 16); }
__device__ __forceinline__ float b2f_hi(u32 u) { return __uint_as_float(u & 0xFFFF0000u); }

__device__ __forceinline__ void expand8(uint4 u, float* f) {
  f[0] = b2f_lo(u.x); f[1] = b2f_hi(u.x);
  f[2] = b2f_lo(u.y); f[3] = b2f_hi(u.y);
  f[4] = b2f_lo(u.z); f[5] = b2f_hi(u.z);
  f[6] = b2f_lo(u.w); f[7] = b2f_hi(u.w);
}

// One wave computes rows [m0,m0+16) x all 64 cols of A(64x64)@W(64x64).
// Arow = A-tile base + m0*LDB (bf16 row-major). Wt = weight bf16, n-major.
// acc[nt] covers cols nt*16..nt*16+15; C layout: row=m0+(lane>>4)*4+r, col=nt*16+(lane&15).
__device__ __forceinline__ void mm16x64(const u16* __restrict__ Arow,
                                        const u16* __restrict__ Wt,
                                        int lane, f32x4 acc[4]) {
  const int m = lane & 15, q = lane >> 4;
  U128 a0, a1;
  a0.u = *(const uint4*)(Arow + m * LDB + q * 8);        // k = q*8
  a1.u = *(const uint4*)(Arow + m * LDB + 32 + q * 8);   // k = 32 + q*8
  #pragma unroll
  for (int nt = 0; nt < 4; ++nt) {
    U128 b0, b1;
    const u16* bp = Wt + (nt * 16 + m) * LDB + q * 8;
    b0.u = *(const uint4*)bp;
    b1.u = *(const uint4*)(bp + 32);
    acc[nt] = __builtin_amdgcn_mfma_f32_16x16x32_bf16(a0.b, b0.b, acc[nt], 0, 0, 0);
    acc[nt] = __builtin_amdgcn_mfma_f32_16x16x32_bf16(a1.b, b1.b, acc[nt], 0, 0, 0);
  }
}

// Stage fp32 weight W[64][64] (k-major) into LDS as bf16 transposed Wt[n][k].
__device__ __forceinline__ void stageW(u16* __restrict__ dst,
                                       const float* __restrict__ W, int t) {
  const int k = t >> 2, nq = t & 3;     // thread owns row k, 16 cols nq*16..
  const float* src = W + k * HD + nq * 16;
  float w[16];
  #pragma unroll
  for (int c = 0; c < 16; c += 4) {
    const float4 v4 = *(const float4*)(src + c);
    w[c] = v4.x; w[c + 1] = v4.y; w[c + 2] = v4.z; w[c + 3] = v4.w;
  }
  #pragma unroll
  for (int j = 0; j < 16; ++j)
    dst[(nq * 16 + j) * LDB + k] = f2b(w[j]);
}

extern "C" __global__ void __launch_bounds__(NTH, 2)
gnn_fused(const float* __restrict__ x, const int* __restrict__ adj,
          const float* __restrict__ W_in, const float* __restrict__ b_in,
          const float* __restrict__ Wq, const float* __restrict__ Wk,
          const float* __restrict__ Wv, const float* __restrict__ Wo,
          const float* __restrict__ bo, const float* __restrict__ ln_g,
          const float* __restrict__ ln_b, const float* __restrict__ Wp1,
          const float* __restrict__ bp1, const float* __restrict__ Wp2,
          const float* __restrict__ bp2, float* __restrict__ out) {
  __shared__ Smem s;
  const int t    = threadIdx.x;
  const int lane = t & 63;
  const int wv   = t >> 6;      // wave id 0..3
  const int m0   = wv * 16;     // GEMM row strip
  const int eg   = (int)blockIdx.x;

  // ---------------- phase 0: mask, x staging, stage Wq[0]
  if (t < NB) {
    u64 mm = 0ull;
    const int4* ap = (const int4*)(adj + t * NB);
    #pragma unroll
    for (int c4 = 0; c4 < 16; ++c4) {
      const int4 a4 = ap[c4];
      if (a4.x) mm |= 1ull << (c4 * 4 + 0);
      if (a4.y) mm |= 1ull << (c4 * 4 + 1);
      if (a4.z) mm |= 1ull << (c4 * 4 + 2);
      if (a4.w) mm |= 1ull << (c4 * 4 + 3);
    }
    s.mask[t] = mm;
  }
  if (t < (NB * FIN) / 4)   // x -> sKf scratch (768 floats)
    ((float4*)s.Kf)[t] = ((const float4*)(x + eg * NB * FIN))[t];
  stageW(s.Wt, Wq, t);      // layer-0 Wq
  __syncthreads();

  // ---------------- input projection: h = x @ W_in + b_in (fp32 vector; K=12)
  {
    const int tr = t >> 4, tc = t & 15;
    const int r0 = tr * 4, c0 = tc * 4;
    float acc[4][4] = {};
    #pragma unroll
    for (int kk = 0; kk < FIN; kk += 4) {
      float a[4][4], b[4][4];
      #pragma unroll
      for (int ii = 0; ii < 4; ++ii) {
        const float4 v4 = *(const float4*)&s.Kf[(r0 + ii) * FIN + kk];
        a[ii][0] = v4.x; a[ii][1] = v4.y; a[ii][2] = v4.z; a[ii][3] = v4.w;
      }
      #pragma unroll
      for (int kt = 0; kt < 4; ++kt) {
        const float4 v4 = *(const float4*)&W_in[(kk + kt) * HD + c0];
        b[kt][0] = v4.x; b[kt][1] = v4.y; b[kt][2] = v4.z; b[kt][3] = v4.w;
      }
      #pragma unroll
      for (int ii = 0; ii < 4; ++ii)
        #pragma unroll
        for (int kt = 0; kt < 4; ++kt)
          #pragma unroll
          for (int jj = 0; jj < 4; ++jj)
            acc[ii][jj] = fmaf(a[ii][kt], b[kt][jj], acc[ii][jj]);
    }
    const float4 bv = *(const float4*)&b_in[c0];
    const float bb[4] = {bv.x, bv.y, bv.z, bv.w};
    #pragma unroll
    for (int ii = 0; ii < 4; ++ii) {
      const int row = r0 + ii;
      float4 o4;
      o4.x = acc[ii][0] + bb[0]; o4.y = acc[ii][1] + bb[1];
      o4.z = acc[ii][2] + bb[2]; o4.w = acc[ii][3] + bb[3];
      *(float4*)&s.H[row * LDF + c0] = o4;
      u32* hb = (u32*)&s.Hb[row * LDB + c0];
      hb[0] = f2b2(o4.x, o4.y);
      hb[1] = f2b2(o4.z, o4.w);
    }
  }
  __syncthreads();

  // ---------------- transformer layers
  for (int l = 0; l < NLAYERS; ++l) {
    const int lo = l * HD * HD;

    // q = h @ Wq  -> Qb (bf16)          [Wt already = Wq[l]]
    {
      f32x4 acc[4] = {{0.f,0.f,0.f,0.f},{0.f,0.f,0.f,0.f},{0.f,0.f,0.f,0.f},{0.f,0.f,0.f,0.f}};
      mm16x64(s.Hb + m0 * LDB, s.Wt, lane, acc);
      const int m = lane & 15, q = lane >> 4;
      #pragma unroll
      for (int nt = 0; nt < 4; ++nt)
        #pragma unroll
        for (int r = 0; r < 4; ++r)
          s.Qb[(m0 + q * 4 + r) * LDB + nt * 16 + m] = f2b(acc[nt][r]);
    }
    __syncthreads();
    stageW(s.Wt, Wk + lo, t);
    __syncthreads();

    // k = h @ Wk  -> Kf (fp32)
    {
      f32x4 acc[4] = {{0.f,0.f,0.f,0.f},{0.f,0.f,0.f,0.f},{0.f,0.f,0.f,0.f},{0.f,0.f,0.f,0.f}};
      mm16x64(s.Hb + m0 * LDB, s.Wt, lane, acc);
      const int m = lane & 15, q = lane >> 4;
      #pragma unroll
      for (int nt = 0; nt < 4; ++nt)
        #pragma unroll
        for (int r = 0; r < 4; ++r)
          s.Kf[(m0 + q * 4 + r) * LDF + nt * 16 + m] = acc[nt][r];
    }
    __syncthreads();
    stageW(s.Wt, Wv + lo, t);
    __syncthreads();

    // v = h @ Wv  -> Vf (fp32)
    {
      f32x4 acc[4] = {{0.f,0.f,0.f,0.f},{0.f,0.f,0.f,0.f},{0.f,0.f,0.f,0.f},{0.f,0.f,0.f,0.f}};
      mm16x64(s.Hb + m0 * LDB, s.Wt, lane, acc);
      const int m = lane & 15, q = lane >> 4;
      #pragma unroll
      for (int nt = 0; nt < 4; ++nt)
        #pragma unroll
        for (int r = 0; r < 4; ++r)
          s.Vf[(m0 + q * 4 + r) * LDF + nt * 16 + m] = acc[nt][r];
    }
    __syncthreads();

    // stage Wo (Wt free), then sparse masked attention (no online max: |s|<=~10)
    stageW(s.Wt, Wo + lo, t);
    {
      const int hh = t >> 6, i = t & 63;
      const u32* qp = (const u32*)&s.Qb[i * LDB + hh * DHEAD];
      uint4 qa = *(const uint4*)qp;
      uint4 qc = *(const uint4*)(qp + 4);
      float qv[16];
      expand8(qa, qv); expand8(qc, qv + 8);

      u64 m = s.mask[i];
      float sum = 0.0f;
      float o[16];
      #pragma unroll
      for (int c = 0; c < 16; ++c) o[c] = 0.0f;

      while (m) {
        const int j = __builtin_ctzll(m);
        m &= (m - 1);
        const float* kp = &s.Kf[j * LDF + hh * DHEAD];
        float sc = 0.0f;
        #pragma unroll
        for (int c = 0; c < 16; c += 4) {
          const float4 k4 = *(const float4*)(kp + c);
          sc = fmaf(qv[c],     k4.x, sc); sc = fmaf(qv[c + 1], k4.y, sc);
          sc = fmaf(qv[c + 2], k4.z, sc); sc = fmaf(qv[c + 3], k4.w, sc);
        }
        const float p = __expf(sc * 0.25f);
        sum += p;
        const float* vp = &s.Vf[j * LDF + hh * DHEAD];
        #pragma unroll
        for (int c = 0; c < 16; c += 4) {
          const float4 v4 = *(const float4*)(vp + c);
          o[c]     = fmaf(p, v4.x, o[c]);
          o[c + 1] = fmaf(p, v4.y, o[c + 1]);
          o[c + 2] = fmaf(p, v4.z, o[c + 2]);
          o[c + 3] = fmaf(p, v4.w, o[c + 3]);
        }
      }
      const float rinv = 1.0f / sum;
      u32* op = (u32*)&s.Qb[i * LDB + hh * DHEAD];
      #pragma unroll
      for (int c = 0; c < 16; c += 2)
        op[c >> 1] = f2b2(o[c] * rinv, o[c + 1] * rinv);
    }
    __syncthreads();

    // u = h + o @ Wo + bo  -> H in-place (each lane touches only its own cells)
    {
      f32x4 acc[4] = {{0.f,0.f,0.f,0.f},{0.f,0.f,0.f,0.f},{0.f,0.f,0.f,0.f},{0.f,0.f,0.f,0.f}};
      mm16x64(s.Qb + m0 * LDB, s.Wt, lane, acc);
      const int m = lane & 15, q = lane >> 4;
      float bov[4];
      #pragma unroll
      for (int nt = 0; nt < 4; ++nt) bov[nt] = bo[l * HD + nt * 16 + m];
      #pragma unroll
      for (int nt = 0; nt < 4; ++nt)
        #pragma unroll
        for (int r = 0; r < 4; ++r) {
          const int idx = (m0 + q * 4 + r) * LDF + nt * 16 + m;
          s.H[idx] = s.H[idx] + acc[nt][r] + bov[nt];
        }
    }
    __syncthreads();

    // LN over rows of H (=u) -> H (=h) + Hb; stage next layer's Wq meanwhile
    if (l + 1 < NLAYERS) stageW(s.Wt, Wq + (l + 1) * HD * HD, t);
    {
      const int i = t >> 2, q4 = t & 3;
      float* up = &s.H[i * LDF + q4 * 16];
      float uv[16];
      #pragma unroll
      for (int c = 0; c < 16; c += 4) {
        const float4 v4 = *(const float4*)(up + c);
        uv[c] = v4.x; uv[c + 1] = v4.y; uv[c + 2] = v4.z; uv[c + 3] = v4.w;
      }
      float s1 = 0.0f, s2 = 0.0f;
      #pragma unroll
      for (int c = 0; c < 16; ++c) { s1 += uv[c]; s2 += uv[c] * uv[c]; }
      s1 += __shfl_xor(s1, 1, 64); s1 += __shfl_xor(s1, 2, 64);
      s2 += __shfl_xor(s2, 1, 64); s2 += __shfl_xor(s2, 2, 64);
      const float mu  = s1 * (1.0f / 64.0f);
      const float var = s2 * (1.0f / 64.0f) - mu * mu;
      const float rs  = rsqrtf(var + LN_EPS);
      const float* gg = ln_g + l * HD + q4 * 16;
      const float* bb = ln_b + l * HD + q4 * 16;
      u32* hb = (u32*)&s.Hb[i * LDB + q4 * 16];
      #pragma unroll
      for (int c = 0; c < 16; c += 4) {
        const float4 g4 = *(const float4*)(gg + c);
        const float4 b4 = *(const float4*)(bb + c);
        float4 o4;
        o4.x = (uv[c]     - mu) * rs * g4.x + b4.x;
        o4.y = (uv[c + 1] - mu) * rs * g4.y + b4.y;
        o4.z = (uv[c + 2] - mu) * rs * g4.z + b4.z;
        o4.w = (uv[c + 3] - mu) * rs * g4.w + b4.w;
        *(float4*)(up + c) = o4;
        hb[(c >> 1)]     = f2b2(o4.x, o4.y);
        hb[(c >> 1) + 1] = f2b2(o4.z, o4.w);
      }
    }
    __syncthreads();
  }

  // ---------------- head
  if (t < HD) {
    float sum = 0.0f;
    #pragma unroll 8
    for (int i = 0; i < NB; ++i) sum += s.H[i * LDF + t];
    s.pool[t] = sum * (1.0f / 64.0f);
  }
  __syncthreads();
  if (t < HD) {
    float acc = bp1[t];
    #pragma unroll 8
    for (int k = 0; k < HD; ++k) acc = fmaf(s.pool[k], Wp1[k * HD + t], acc);
    s.y1[t] = fmaxf(acc, 0.0f);
  }
  __syncthreads();
  if (t < ODIM) {
    float acc = bp2[t];
    #pragma unroll 8
    for (int c = 0; c < HD; ++c) acc = fmaf(s.y1[c], Wp2[c * ODIM + t], acc);
    out[eg * ODIM + t] = acc;
  }
}

extern "C" void kernel_launch(void* const* d_in, const int* in_sizes, int n_in,
                              void* d_out, int out_size, void* d_ws, size_t ws_size,
                              hipStream_t stream) {
  const float* x    = (const float*)d_in[0];
  const int*   adj  = (const int*)d_in[1];
  const float* W_in = (const float*)d_in[2];
  const float* b_in = (const float*)d_in[3];
  const float* Wq   = (const float*)d_in[4];
  const float* Wk   = (const float*)d_in[5];
  const float* Wv   = (const float*)d_in[6];
  const float* Wo   = (const float*)d_in[7];
  const float* bo   = (const float*)d_in[8];
  const float* lng  = (const float*)d_in[9];
  const float* lnb  = (const float*)d_in[10];
  const float* Wp1  = (const float*)d_in[11];
  const float* bp1  = (const float*)d_in[12];
  const float* Wp2  = (const float*)d_in[13];
  const float* bp2  = (const float*)d_in[14];
  float* outp = (float*)d_out;

  dim3 grid(BTOT), block(NTH);
  hipLaunchKernelGGL(gnn_fused, grid, block, 0, stream,
                     x, adj, W_in, b_in, Wq, Wk, Wv, Wo, bo, lng, lnb,
                     Wp1, bp1, Wp2, bp2, outp);
}

// Round 3
// 405.581 us; speedup vs baseline: 2.6112x; 1.2096x over previous
//
#include <hip/hip_runtime.h>
#include <stdint.h>

// Problem constants
#define NB       64
#define FIN      12
#define HD       64
#define NHEADS   4
#define DHEAD    16
#define NLAYERS  3
#define ODIM     128
#define LN_EPS   1e-5f
#define BTOT     8192

#define LDF      68    // fp32 tile row stride (floats): 272 B rows, 16B-aligned, 2-way banks
#define LDB      72    // bf16 tile row stride (elems): 144 B rows, 16B-aligned
#define NTH      256   // 4 waves, one batch element per block
#define NW       (NLAYERS * 4)   // packed weights: (Wq,Wk,Wv,Wo) x 3 layers
#define WFRAG    4096            // u16 per weight in B-fragment order

typedef unsigned int       u32;
typedef unsigned short     u16;
typedef unsigned long long u64;

typedef __bf16 bf16x8 __attribute__((ext_vector_type(8)));
typedef float  f32x4  __attribute__((ext_vector_type(4)));
union U128 { uint4 u; bf16x8 b; };

struct __align__(16) Smem {
  float H [NB * LDF];   // 17408  residual h (fp32), u in-place pre-LN
  float Kf[NB * LDF];   // 17408  k fp32 (x staging in phase 0)
  float Vf[NB * LDF];   // 17408  v fp32
  u16   Hb[NB * LDB];   //  9216  h bf16 (MFMA A source)
  u16   Qb[NB * LDB];   //  9216  q bf16, then attention output o
  u64   mask[NB];       //   512
  float pool[HD];       //   256
  float y1[HD];         //   256
};                      // 71680 B -> 2 blocks/CU

// fp32 -> bf16 RNE
__device__ __forceinline__ u16 f2b(float f) {
  u32 u = __float_as_uint(f);
  return (u16)((u + 0x7FFFu + ((u >> 16) & 1u)) >> 16);
}
__device__ __forceinline__ u32 f2b2(float lo, float hi) {
  return (u32)f2b(lo) | ((u32)f2b(hi) << 16);
}
__device__ __forceinline__ float b2f_lo(u32 u) { return __uint_as_float(u << 16); }
__device__ __forceinline__ float b2f_hi(u32 u) { return __uint_as_float(u & 0xFFFF0000u); }
__device__ __forceinline__ void expand8(uint4 u, float* f) {
  f[0] = b2f_lo(u.x); f[1] = b2f_hi(u.x);
  f[2] = b2f_lo(u.y); f[3] = b2f_hi(u.y);
  f[4] = b2f_lo(u.z); f[5] = b2f_hi(u.z);
  f[6] = b2f_lo(u.w); f[7] = b2f_hi(u.w);
}

// ---------------- prep kernel: pack 12 weights into bf16 B-fragment order ---------
// frag f (0..511): lane=f&63, kh=(f>>6)&1, nt=f>>7
// element j: B[n = nt*16+(lane&15)][k = kh*32+(lane>>4)*8+j]  (src is k-major W[k][n])
extern "C" __global__ void __launch_bounds__(256)
prep_weights(const float* __restrict__ Wq, const float* __restrict__ Wk,
             const float* __restrict__ Wv, const float* __restrict__ Wo,
             u16* __restrict__ wsW) {
  const int w = blockIdx.x;             // 0..11
  const int l = w >> 2, ty = w & 3;
  const float* src = (ty == 0 ? Wq : ty == 1 ? Wk : ty == 2 ? Wv : Wo) + l * HD * HD;
  u16* dst = wsW + w * WFRAG;
  for (int f = threadIdx.x; f < 512; f += 256) {
    const int lane = f & 63, kh = (f >> 6) & 1, nt = f >> 7;
    const int n  = nt * 16 + (lane & 15);
    const int k0 = kh * 32 + ((lane >> 4) & 3) * 8;
    u16 tmp[8];
    #pragma unroll
    for (int j = 0; j < 8; ++j) tmp[j] = f2b(src[(k0 + j) * HD + n]);
    *(uint4*)(dst + f * 8) = *(const uint4*)tmp;
  }
}

// wave computes rows [m0,m0+16) x 64 cols of A @ W; A-frags preloaded (a0: k0..31, a1: k32..63),
// B-frags from global fragment-ordered wf. C: row=m0+(lane>>4)*4+r, col=nt*16+(lane&15).
__device__ __forceinline__ void mm16x64g(U128 a0, U128 a1,
                                         const u16* __restrict__ wf,
                                         int lane, f32x4 acc[4]) {
  #pragma unroll
  for (int nt = 0; nt < 4; ++nt) {
    U128 b0, b1;
    b0.u = *(const uint4*)(wf + ((nt * 2 + 0) * 64 + lane) * 8);
    b1.u = *(const uint4*)(wf + ((nt * 2 + 1) * 64 + lane) * 8);
    acc[nt] = __builtin_amdgcn_mfma_f32_16x16x32_bf16(a0.b, b0.b, acc[nt], 0, 0, 0);
    acc[nt] = __builtin_amdgcn_mfma_f32_16x16x32_bf16(a1.b, b1.b, acc[nt], 0, 0, 0);
  }
}

extern "C" __global__ void __launch_bounds__(NTH, 2)
gnn_fused(const float* __restrict__ x, const int* __restrict__ adj,
          const float* __restrict__ W_in, const float* __restrict__ b_in,
          const u16* __restrict__ wsW, const float* __restrict__ bo,
          const float* __restrict__ ln_g, const float* __restrict__ ln_b,
          const float* __restrict__ Wp1, const float* __restrict__ bp1,
          const float* __restrict__ Wp2, const float* __restrict__ bp2,
          float* __restrict__ out) {
  __shared__ Smem s;
  const int t    = threadIdx.x;
  const int lane = t & 63;
  const int wv   = t >> 6;
  const int m0   = wv * 16;
  const int eg   = (int)blockIdx.x;

  // ---------------- phase 0: mask + x staging
  if (t < NB) {
    u64 mm = 0ull;
    const int4* ap = (const int4*)(adj + t * NB);
    #pragma unroll
    for (int c4 = 0; c4 < 16; ++c4) {
      const int4 a4 = ap[c4];
      if (a4.x) mm |= 1ull << (c4 * 4 + 0);
      if (a4.y) mm |= 1ull << (c4 * 4 + 1);
      if (a4.z) mm |= 1ull << (c4 * 4 + 2);
      if (a4.w) mm |= 1ull << (c4 * 4 + 3);
    }
    s.mask[t] = mm;
  }
  if (t < (NB * FIN) / 4)
    ((float4*)s.Kf)[t] = ((const float4*)(x + eg * NB * FIN))[t];
  __syncthreads();

  // ---------------- input projection: h = x @ W_in + b_in (fp32 vector, K=12)
  {
    const int tr = t >> 4, tc = t & 15;
    const int r0 = tr * 4, c0 = tc * 4;
    float acc[4][4] = {};
    #pragma unroll
    for (int kk = 0; kk < FIN; kk += 4) {
      float a[4][4], b[4][4];
      #pragma unroll
      for (int ii = 0; ii < 4; ++ii) {
        const float4 v4 = *(const float4*)&s.Kf[(r0 + ii) * FIN + kk];
        a[ii][0] = v4.x; a[ii][1] = v4.y; a[ii][2] = v4.z; a[ii][3] = v4.w;
      }
      #pragma unroll
      for (int kt = 0; kt < 4; ++kt) {
        const float4 v4 = *(const float4*)&W_in[(kk + kt) * HD + c0];
        b[kt][0] = v4.x; b[kt][1] = v4.y; b[kt][2] = v4.z; b[kt][3] = v4.w;
      }
      #pragma unroll
      for (int ii = 0; ii < 4; ++ii)
        #pragma unroll
        for (int kt = 0; kt < 4; ++kt)
          #pragma unroll
          for (int jj = 0; jj < 4; ++jj)
            acc[ii][jj] = fmaf(a[ii][kt], b[kt][jj], acc[ii][jj]);
    }
    const float4 bv = *(const float4*)&b_in[c0];
    const float bb[4] = {bv.x, bv.y, bv.z, bv.w};
    #pragma unroll
    for (int ii = 0; ii < 4; ++ii) {
      const int row = r0 + ii;
      float4 o4;
      o4.x = acc[ii][0] + bb[0]; o4.y = acc[ii][1] + bb[1];
      o4.z = acc[ii][2] + bb[2]; o4.w = acc[ii][3] + bb[3];
      *(float4*)&s.H[row * LDF + c0] = o4;
      u32* hb = (u32*)&s.Hb[row * LDB + c0];
      hb[0] = f2b2(o4.x, o4.y);
      hb[1] = f2b2(o4.z, o4.w);
    }
  }
  __syncthreads();

  // ---------------- transformer layers
  for (int l = 0; l < NLAYERS; ++l) {
    const u16* wl = wsW + (l * 4) * WFRAG;
    const int m = lane & 15, q = lane >> 4;

    // fused q/k/v projections (shared A-fragments, immediate writeback each)
    {
      U128 a0, a1;
      const u16* ar = &s.Hb[(m0 + m) * LDB + q * 8];
      a0.u = *(const uint4*)ar;
      a1.u = *(const uint4*)(ar + 32);

      f32x4 aq[4] = {{0,0,0,0},{0,0,0,0},{0,0,0,0},{0,0,0,0}};
      mm16x64g(a0, a1, wl + 0 * WFRAG, lane, aq);
      #pragma unroll
      for (int nt = 0; nt < 4; ++nt)
        #pragma unroll
        for (int r = 0; r < 4; ++r)
          s.Qb[(m0 + q * 4 + r) * LDB + nt * 16 + m] = f2b(aq[nt][r]);

      f32x4 ak[4] = {{0,0,0,0},{0,0,0,0},{0,0,0,0},{0,0,0,0}};
      mm16x64g(a0, a1, wl + 1 * WFRAG, lane, ak);
      #pragma unroll
      for (int nt = 0; nt < 4; ++nt)
        #pragma unroll
        for (int r = 0; r < 4; ++r)
          s.Kf[(m0 + q * 4 + r) * LDF + nt * 16 + m] = ak[nt][r];

      f32x4 av[4] = {{0,0,0,0},{0,0,0,0},{0,0,0,0},{0,0,0,0}};
      mm16x64g(a0, a1, wl + 2 * WFRAG, lane, av);
      #pragma unroll
      for (int nt = 0; nt < 4; ++nt)
        #pragma unroll
        for (int r = 0; r < 4; ++r)
          s.Vf[(m0 + q * 4 + r) * LDF + nt * 16 + m] = av[nt][r];
    }
    __syncthreads();

    // sparse masked attention (<=9 neighbors/row; scores bounded -> plain softmax)
    {
      const int hh = t >> 6, i = t & 63;
      const u32* qp = (const u32*)&s.Qb[i * LDB + hh * DHEAD];
      uint4 qa = *(const uint4*)qp;
      uint4 qc = *(const uint4*)(qp + 4);
      float qv[16];
      expand8(qa, qv); expand8(qc, qv + 8);

      u64 mk = s.mask[i];
      float sum = 0.0f;
      float o[16];
      #pragma unroll
      for (int c = 0; c < 16; ++c) o[c] = 0.0f;

      while (mk) {
        const int j = __builtin_ctzll(mk);
        mk &= (mk - 1);
        const float* kp = &s.Kf[j * LDF + hh * DHEAD];
        float sc = 0.0f;
        #pragma unroll
        for (int c = 0; c < 16; c += 4) {
          const float4 k4 = *(const float4*)(kp + c);
          sc = fmaf(qv[c],     k4.x, sc); sc = fmaf(qv[c + 1], k4.y, sc);
          sc = fmaf(qv[c + 2], k4.z, sc); sc = fmaf(qv[c + 3], k4.w, sc);
        }
        const float p = __expf(sc * 0.25f);
        sum += p;
        const float* vp = &s.Vf[j * LDF + hh * DHEAD];
        #pragma unroll
        for (int c = 0; c < 16; c += 4) {
          const float4 v4 = *(const float4*)(vp + c);
          o[c]     = fmaf(p, v4.x, o[c]);
          o[c + 1] = fmaf(p, v4.y, o[c + 1]);
          o[c + 2] = fmaf(p, v4.z, o[c + 2]);
          o[c + 3] = fmaf(p, v4.w, o[c + 3]);
        }
      }
      const float rinv = 1.0f / sum;
      u32 ob[8];
      #pragma unroll
      for (int c = 0; c < 16; c += 2)
        ob[c >> 1] = f2b2(o[c] * rinv, o[c + 1] * rinv);
      uint4* op = (uint4*)&s.Qb[i * LDB + hh * DHEAD];
      op[0] = make_uint4(ob[0], ob[1], ob[2], ob[3]);
      op[1] = make_uint4(ob[4], ob[5], ob[6], ob[7]);
    }
    __syncthreads();

    // u = h + o @ Wo + bo  (RMW H in C-fragment cells; wave-exclusive rows)
    {
      const int m = lane & 15, q = lane >> 4;
      U128 a0, a1;
      const u16* ar = &s.Qb[(m0 + m) * LDB + q * 8];
      a0.u = *(const uint4*)ar;
      a1.u = *(const uint4*)(ar + 32);
      f32x4 ao[4] = {{0,0,0,0},{0,0,0,0},{0,0,0,0},{0,0,0,0}};
      mm16x64g(a0, a1, wl + 3 * WFRAG, lane, ao);
      float bov[4];
      #pragma unroll
      for (int nt = 0; nt < 4; ++nt) bov[nt] = bo[l * HD + nt * 16 + m];
      #pragma unroll
      for (int nt = 0; nt < 4; ++nt)
        #pragma unroll
        for (int r = 0; r < 4; ++r) {
          const int idx = (m0 + q * 4 + r) * LDF + nt * 16 + m;
          s.H[idx] = s.H[idx] + ao[nt][r] + bov[nt];
        }
    }
    __syncthreads();

    // h = LN(u)*g + b  -> H + Hb
    {
      const int i = t >> 2, q4 = t & 3;
      float* up = &s.H[i * LDF + q4 * 16];
      float uv[16];
      #pragma unroll
      for (int c = 0; c < 16; c += 4) {
        const float4 v4 = *(const float4*)(up + c);
        uv[c] = v4.x; uv[c + 1] = v4.y; uv[c + 2] = v4.z; uv[c + 3] = v4.w;
      }
      float s1 = 0.0f, s2 = 0.0f;
      #pragma unroll
      for (int c = 0; c < 16; ++c) { s1 += uv[c]; s2 += uv[c] * uv[c]; }
      s1 += __shfl_xor(s1, 1, 64); s1 += __shfl_xor(s1, 2, 64);
      s2 += __shfl_xor(s2, 1, 64); s2 += __shfl_xor(s2, 2, 64);
      const float mu  = s1 * (1.0f / 64.0f);
      const float var = s2 * (1.0f / 64.0f) - mu * mu;
      const float rs  = rsqrtf(var + LN_EPS);
      const float* gg = ln_g + l * HD + q4 * 16;
      const float* bb = ln_b + l * HD + q4 * 16;
      u32* hb = (u32*)&s.Hb[i * LDB + q4 * 16];
      #pragma unroll
      for (int c = 0; c < 16; c += 4) {
        const float4 g4 = *(const float4*)(gg + c);
        const float4 b4 = *(const float4*)(bb + c);
        float4 o4;
        o4.x = (uv[c]     - mu) * rs * g4.x + b4.x;
        o4.y = (uv[c + 1] - mu) * rs * g4.y + b4.y;
        o4.z = (uv[c + 2] - mu) * rs * g4.z + b4.z;
        o4.w = (uv[c + 3] - mu) * rs * g4.w + b4.w;
        *(float4*)(up + c) = o4;
        hb[(c >> 1)]     = f2b2(o4.x, o4.y);
        hb[(c >> 1) + 1] = f2b2(o4.z, o4.w);
      }
    }
    __syncthreads();
  }

  // ---------------- head
  if (t < HD) {
    float sum = 0.0f;
    #pragma unroll 8
    for (int i = 0; i < NB; ++i) sum += s.H[i * LDF + t];
    s.pool[t] = sum * (1.0f / 64.0f);
  }
  __syncthreads();
  if (t < HD) {
    float acc = bp1[t];
    #pragma unroll 8
    for (int k = 0; k < HD; ++k) acc = fmaf(s.pool[k], Wp1[k * HD + t], acc);
    s.y1[t] = fmaxf(acc, 0.0f);
  }
  __syncthreads();
  if (t < ODIM) {
    float acc = bp2[t];
    #pragma unroll 8
    for (int c = 0; c < HD; ++c) acc = fmaf(s.y1[c], Wp2[c * ODIM + t], acc);
    out[eg * ODIM + t] = acc;
  }
}

extern "C" void kernel_launch(void* const* d_in, const int* in_sizes, int n_in,
                              void* d_out, int out_size, void* d_ws, size_t ws_size,
                              hipStream_t stream) {
  const float* x    = (const float*)d_in[0];
  const int*   adj  = (const int*)d_in[1];
  const float* W_in = (const float*)d_in[2];
  const float* b_in = (const float*)d_in[3];
  const float* Wq   = (const float*)d_in[4];
  const float* Wk   = (const float*)d_in[5];
  const float* Wv   = (const float*)d_in[6];
  const float* Wo   = (const float*)d_in[7];
  const float* bo   = (const float*)d_in[8];
  const float* lng  = (const float*)d_in[9];
  const float* lnb  = (const float*)d_in[10];
  const float* Wp1  = (const float*)d_in[11];
  const float* bp1  = (const float*)d_in[12];
  const float* Wp2  = (const float*)d_in[13];
  const float* bp2  = (const float*)d_in[14];
  float* outp = (float*)d_out;
  u16*   wsW  = (u16*)d_ws;   // 12 * 4096 u16 = 98304 B

  hipLaunchKernelGGL(prep_weights, dim3(NW), dim3(256), 0, stream,
                     Wq, Wk, Wv, Wo, wsW);
  hipLaunchKernelGGL(gnn_fused, dim3(BTOT), dim3(NTH), 0, stream,
                     x, adj, W_in, b_in, wsW, bo, lng, lnb,
                     Wp1, bp1, Wp2, bp2, outp);
}

// Round 4
// 382.591 us; speedup vs baseline: 2.7682x; 1.0601x over previous
//
#include <hip/hip_runtime.h>
#include <stdint.h>

// Problem constants
#define NB       64
#define FIN      12
#define HD       64
#define NHEADS   4
#define DHEAD    16
#define NLAYERS  3
#define ODIM     128
#define LN_EPS   1e-5f
#define BTOT     8192

#define LDF      68    // fp32 LDS row stride (floats)
#define LDB      72    // bf16 LDS row stride (elems)
#define NTH      256
#define NW       (NLAYERS * 4)
#define WFRAG    4096

typedef unsigned int       u32;
typedef unsigned short     u16;
typedef unsigned long long u64;

typedef __bf16 bf16x8 __attribute__((ext_vector_type(8)));
typedef float  f32x4  __attribute__((ext_vector_type(4)));
union U128 { uint4 u; bf16x8 b; };

#if __has_builtin(__builtin_amdgcn_exp2f)
  #define QSCALE (0.25f * 1.44269504f)   // fold softmax scale * log2(e) into q
  __device__ __forceinline__ float edge_exp(float x) { return __builtin_amdgcn_exp2f(x); }
#else
  #define QSCALE 0.25f
  __device__ __forceinline__ float edge_exp(float x) { return __expf(x); }
#endif

struct __align__(16) Smem {
  float Kf[NB * LDF];     // 17408  k fp32 (x staging in phase 0)
  float Vf[NB * LDF];     // 17408  v fp32
  u16   Hb[NB * LDB];     //  9216  h bf16 (MFMA A source)
  u16   Qb[NB * LDB];     //  9216  q bf16, then attention output o
  union {                 //   512  disjoint lifetimes
    u64 mask[NB];                       // layers phase
    struct { float pool[HD]; float y1[HD]; } hp;  // head phase
  } u;
};                        // 53760 B -> 3 blocks/CU

// fp32 -> bf16 RNE
__device__ __forceinline__ u16 f2b(float f) {
  u32 u = __float_as_uint(f);
  return (u16)((u + 0x7FFFu + ((u >> 16) & 1u)) >> 16);
}
__device__ __forceinline__ u32 f2b2(float lo, float hi) {
  return (u32)f2b(lo) | ((u32)f2b(hi) << 16);
}
__device__ __forceinline__ float b2f_lo(u32 u) { return __uint_as_float(u << 16); }
__device__ __forceinline__ float b2f_hi(u32 u) { return __uint_as_float(u & 0xFFFF0000u); }
__device__ __forceinline__ void expand8(uint4 u, float* f) {
  f[0] = b2f_lo(u.x); f[1] = b2f_hi(u.x);
  f[2] = b2f_lo(u.y); f[3] = b2f_hi(u.y);
  f[4] = b2f_lo(u.z); f[5] = b2f_hi(u.z);
  f[6] = b2f_lo(u.w); f[7] = b2f_hi(u.w);
}

// ---------------- prep kernel: pack 12 weights into bf16 B-fragment order
extern "C" __global__ void __launch_bounds__(256)
prep_weights(const float* __restrict__ Wq, const float* __restrict__ Wk,
             const float* __restrict__ Wv, const float* __restrict__ Wo,
             u16* __restrict__ wsW) {
  const int w = blockIdx.x;             // 0..11
  const int l = w >> 2, ty = w & 3;
  const float* src = (ty == 0 ? Wq : ty == 1 ? Wk : ty == 2 ? Wv : Wo) + l * HD * HD;
  u16* dst = wsW + w * WFRAG;
  for (int f = threadIdx.x; f < 512; f += 256) {
    const int lane = f & 63, kh = (f >> 6) & 1, nt = f >> 7;
    const int n  = nt * 16 + (lane & 15);
    const int k0 = kh * 32 + ((lane >> 4) & 3) * 8;
    u16 tmp[8];
    #pragma unroll
    for (int j = 0; j < 8; ++j) tmp[j] = f2b(src[(k0 + j) * HD + n]);
    *(uint4*)(dst + f * 8) = *(const uint4*)tmp;
  }
}

// wave: rows [m0,m0+16) x 64 cols of A @ W. A-frags preloaded; B-frags global.
// C layout: row = m0 + (lane>>4)*4 + r, col = nt*16 + (lane&15).
__device__ __forceinline__ void mm16x64g(U128 a0, U128 a1,
                                         const u16* __restrict__ wf,
                                         int lane, f32x4 acc[4]) {
  #pragma unroll
  for (int nt = 0; nt < 4; ++nt) {
    U128 b0, b1;
    b0.u = *(const uint4*)(wf + ((nt * 2 + 0) * 64 + lane) * 8);
    b1.u = *(const uint4*)(wf + ((nt * 2 + 1) * 64 + lane) * 8);
    acc[nt] = __builtin_amdgcn_mfma_f32_16x16x32_bf16(a0.b, b0.b, acc[nt], 0, 0, 0);
    acc[nt] = __builtin_amdgcn_mfma_f32_16x16x32_bf16(a1.b, b1.b, acc[nt], 0, 0, 0);
  }
}

// one attention edge: score = qv . k (4 split accumulators), p = exp, o += p*v
__device__ __forceinline__ void attn_edge(const float* __restrict__ qv,
                                          float4 ka, float4 kb, float4 kc, float4 kd,
                                          float4 va, float4 vb, float4 vc, float4 vd,
                                          float& sum, float* __restrict__ o) {
  float d0, d1, d2, d3;
  d0 = qv[0]  * ka.x; d0 = fmaf(qv[1],  ka.y, d0); d0 = fmaf(qv[2],  ka.z, d0); d0 = fmaf(qv[3],  ka.w, d0);
  d1 = qv[4]  * kb.x; d1 = fmaf(qv[5],  kb.y, d1); d1 = fmaf(qv[6],  kb.z, d1); d1 = fmaf(qv[7],  kb.w, d1);
  d2 = qv[8]  * kc.x; d2 = fmaf(qv[9],  kc.y, d2); d2 = fmaf(qv[10], kc.z, d2); d2 = fmaf(qv[11], kc.w, d2);
  d3 = qv[12] * kd.x; d3 = fmaf(qv[13], kd.y, d3); d3 = fmaf(qv[14], kd.z, d3); d3 = fmaf(qv[15], kd.w, d3);
  const float p = edge_exp((d0 + d1) + (d2 + d3));
  sum += p;
  o[0]  = fmaf(p, va.x, o[0]);  o[1]  = fmaf(p, va.y, o[1]);
  o[2]  = fmaf(p, va.z, o[2]);  o[3]  = fmaf(p, va.w, o[3]);
  o[4]  = fmaf(p, vb.x, o[4]);  o[5]  = fmaf(p, vb.y, o[5]);
  o[6]  = fmaf(p, vb.z, o[6]);  o[7]  = fmaf(p, vb.w, o[7]);
  o[8]  = fmaf(p, vc.x, o[8]);  o[9]  = fmaf(p, vc.y, o[9]);
  o[10] = fmaf(p, vc.z, o[10]); o[11] = fmaf(p, vc.w, o[11]);
  o[12] = fmaf(p, vd.x, o[12]); o[13] = fmaf(p, vd.y, o[13]);
  o[14] = fmaf(p, vd.z, o[14]); o[15] = fmaf(p, vd.w, o[15]);
}

extern "C" __global__ void __launch_bounds__(NTH, 3)
gnn_fused(const float* __restrict__ x, const int* __restrict__ adj,
          const float* __restrict__ W_in, const float* __restrict__ b_in,
          const u16* __restrict__ wsW, const float* __restrict__ bo,
          const float* __restrict__ ln_g, const float* __restrict__ ln_b,
          const float* __restrict__ Wp1, const float* __restrict__ bp1,
          const float* __restrict__ Wp2, const float* __restrict__ bp2,
          float* __restrict__ out) {
  __shared__ Smem s;
  const int t    = threadIdx.x;
  const int lane = t & 63;
  const int wv   = t >> 6;
  const int m0   = wv * 16;
  const int eg   = (int)blockIdx.x;
  const int m    = lane & 15, q = lane >> 4;

  // ---------------- phase 0: mask + x staging
  if (t < NB) {
    u64 mm = 0ull;
    const int4* ap = (const int4*)(adj + t * NB);
    #pragma unroll
    for (int c4 = 0; c4 < 16; ++c4) {
      const int4 a4 = ap[c4];
      if (a4.x) mm |= 1ull << (c4 * 4 + 0);
      if (a4.y) mm |= 1ull << (c4 * 4 + 1);
      if (a4.z) mm |= 1ull << (c4 * 4 + 2);
      if (a4.w) mm |= 1ull << (c4 * 4 + 3);
    }
    s.u.mask[t] = mm;
  }
  if (t < (NB * FIN) / 4)
    ((float4*)s.Kf)[t] = ((const float4*)(x + eg * NB * FIN))[t];
  __syncthreads();

  // ---------------- input projection in C-fragment layout (fp32): h -> registers
  float hr[4][4];   // [nt][r]: cell (row = m0+q*4+r, col = nt*16+m)
  {
    #pragma unroll
    for (int nt = 0; nt < 4; ++nt)
      #pragma unroll
      for (int r = 0; r < 4; ++r) hr[nt][r] = 0.0f;
    #pragma unroll 4
    for (int k = 0; k < FIN; ++k) {
      float w[4], xv[4];
      #pragma unroll
      for (int nt = 0; nt < 4; ++nt) w[nt] = W_in[k * HD + nt * 16 + m];
      #pragma unroll
      for (int r = 0; r < 4; ++r) xv[r] = s.Kf[(m0 + q * 4 + r) * FIN + k];
      #pragma unroll
      for (int nt = 0; nt < 4; ++nt)
        #pragma unroll
        for (int r = 0; r < 4; ++r) hr[nt][r] = fmaf(xv[r], w[nt], hr[nt][r]);
    }
    #pragma unroll
    for (int nt = 0; nt < 4; ++nt) {
      const float bn = b_in[nt * 16 + m];
      #pragma unroll
      for (int r = 0; r < 4; ++r) {
        hr[nt][r] += bn;
        s.Hb[(m0 + q * 4 + r) * LDB + nt * 16 + m] = f2b(hr[nt][r]);
      }
    }
  }
  __syncthreads();

  // ---------------- transformer layers
  for (int l = 0; l < NLAYERS; ++l) {
    const u16* wl = wsW + (l * 4) * WFRAG;

    // fused q/k/v projections (shared A-fragments)
    {
      U128 a0, a1;
      const u16* ar = &s.Hb[(m0 + m) * LDB + q * 8];
      a0.u = *(const uint4*)ar;
      a1.u = *(const uint4*)(ar + 32);

      f32x4 aq[4] = {{0,0,0,0},{0,0,0,0},{0,0,0,0},{0,0,0,0}};
      mm16x64g(a0, a1, wl + 0 * WFRAG, lane, aq);
      #pragma unroll
      for (int nt = 0; nt < 4; ++nt)
        #pragma unroll
        for (int r = 0; r < 4; ++r)
          s.Qb[(m0 + q * 4 + r) * LDB + nt * 16 + m] = f2b(aq[nt][r]);

      f32x4 ak[4] = {{0,0,0,0},{0,0,0,0},{0,0,0,0},{0,0,0,0}};
      mm16x64g(a0, a1, wl + 1 * WFRAG, lane, ak);
      #pragma unroll
      for (int nt = 0; nt < 4; ++nt)
        #pragma unroll
        for (int r = 0; r < 4; ++r)
          s.Kf[(m0 + q * 4 + r) * LDF + nt * 16 + m] = ak[nt][r];

      f32x4 av[4] = {{0,0,0,0},{0,0,0,0},{0,0,0,0},{0,0,0,0}};
      mm16x64g(a0, a1, wl + 2 * WFRAG, lane, av);
      #pragma unroll
      for (int nt = 0; nt < 4; ++nt)
        #pragma unroll
        for (int r = 0; r < 4; ++r)
          s.Vf[(m0 + q * 4 + r) * LDF + nt * 16 + m] = av[nt][r];
    }
    __syncthreads();

    // sparse masked attention; ping-pong k/v double-buffer across edges
    {
      const int hh = wv, i = lane;
      const u32* qp = (const u32*)&s.Qb[i * LDB + hh * DHEAD];
      uint4 qa = *(const uint4*)qp;
      uint4 qc = *(const uint4*)(qp + 4);
      float qv[16];
      expand8(qa, qv); expand8(qc, qv + 8);
      #pragma unroll
      for (int c = 0; c < 16; ++c) qv[c] *= QSCALE;

      u64 mk = s.u.mask[i];
      float sum = 0.0f;
      float o[16];
      #pragma unroll
      for (int c = 0; c < 16; ++c) o[c] = 0.0f;

      int j = (int)__builtin_ctzll(mk); mk &= mk - 1;
      const float4* kp = (const float4*)&s.Kf[j * LDF + hh * DHEAD];
      const float4* vp = (const float4*)&s.Vf[j * LDF + hh * DHEAD];
      float4 ka = kp[0], kb = kp[1], kc = kp[2], kd = kp[3];
      float4 va = vp[0], vb = vp[1], vc = vp[2], vd = vp[3];

      for (;;) {
        if (!mk) { attn_edge(qv, ka, kb, kc, kd, va, vb, vc, vd, sum, o); break; }
        j = (int)__builtin_ctzll(mk); mk &= mk - 1;
        const float4* kp2 = (const float4*)&s.Kf[j * LDF + hh * DHEAD];
        const float4* vp2 = (const float4*)&s.Vf[j * LDF + hh * DHEAD];
        float4 ka2 = kp2[0], kb2 = kp2[1], kc2 = kp2[2], kd2 = kp2[3];
        float4 va2 = vp2[0], vb2 = vp2[1], vc2 = vp2[2], vd2 = vp2[3];
        attn_edge(qv, ka, kb, kc, kd, va, vb, vc, vd, sum, o);
        if (!mk) { attn_edge(qv, ka2, kb2, kc2, kd2, va2, vb2, vc2, vd2, sum, o); break; }
        j = (int)__builtin_ctzll(mk); mk &= mk - 1;
        kp = (const float4*)&s.Kf[j * LDF + hh * DHEAD];
        vp = (const float4*)&s.Vf[j * LDF + hh * DHEAD];
        ka = kp[0]; kb = kp[1]; kc = kp[2]; kd = kp[3];
        va = vp[0]; vb = vp[1]; vc = vp[2]; vd = vp[3];
        attn_edge(qv, ka2, kb2, kc2, kd2, va2, vb2, vc2, vd2, sum, o);
      }

      const float rinv = 1.0f / sum;
      u32 ob[8];
      #pragma unroll
      for (int c = 0; c < 16; c += 2)
        ob[c >> 1] = f2b2(o[c] * rinv, o[c + 1] * rinv);
      uint4* op = (uint4*)&s.Qb[i * LDB + hh * DHEAD];
      op[0] = make_uint4(ob[0], ob[1], ob[2], ob[3]);
      op[1] = make_uint4(ob[4], ob[5], ob[6], ob[7]);
    }
    __syncthreads();

    // u = h + o @ Wo + bo  (registers), then LN (registers + shfl), h -> hr (+Hb)
    {
      U128 a0, a1;
      const u16* ar = &s.Qb[(m0 + m) * LDB + q * 8];
      a0.u = *(const uint4*)ar;
      a1.u = *(const uint4*)(ar + 32);
      f32x4 ao[4] = {{0,0,0,0},{0,0,0,0},{0,0,0,0},{0,0,0,0}};
      mm16x64g(a0, a1, wl + 3 * WFRAG, lane, ao);

      float uu[4][4];
      #pragma unroll
      for (int nt = 0; nt < 4; ++nt) {
        const float bn = bo[l * HD + nt * 16 + m];
        #pragma unroll
        for (int r = 0; r < 4; ++r)
          uu[nt][r] = hr[nt][r] + ao[nt][r] + bn;
      }
      // LN stats per row r (row elements live in lanes sharing q; cols = nt*16+m)
      float s1[4], s2[4];
      #pragma unroll
      for (int r = 0; r < 4; ++r) {
        s1[r] = ((uu[0][r] + uu[1][r]) + (uu[2][r] + uu[3][r]));
        s2[r] = ((uu[0][r] * uu[0][r] + uu[1][r] * uu[1][r]) +
                 (uu[2][r] * uu[2][r] + uu[3][r] * uu[3][r]));
      }
      #pragma unroll
      for (int d = 1; d < 16; d <<= 1) {
        #pragma unroll
        for (int r = 0; r < 4; ++r) {
          s1[r] += __shfl_xor(s1[r], d, 64);
          s2[r] += __shfl_xor(s2[r], d, 64);
        }
      }
      float mu[4], rs[4];
      #pragma unroll
      for (int r = 0; r < 4; ++r) {
        mu[r] = s1[r] * (1.0f / 64.0f);
        const float var = s2[r] * (1.0f / 64.0f) - mu[r] * mu[r];
        rs[r] = rsqrtf(var + LN_EPS);
      }
      const bool wb = (l + 1 < NLAYERS);
      #pragma unroll
      for (int nt = 0; nt < 4; ++nt) {
        const float gv = ln_g[l * HD + nt * 16 + m];
        const float bv = ln_b[l * HD + nt * 16 + m];
        #pragma unroll
        for (int r = 0; r < 4; ++r) {
          hr[nt][r] = (uu[nt][r] - mu[r]) * rs[r] * gv + bv;
          if (wb) s.Hb[(m0 + q * 4 + r) * LDB + nt * 16 + m] = f2b(hr[nt][r]);
        }
      }
    }
    __syncthreads();
  }

  // ---------------- head: pool (registers + LDS atomics) -> MLP
  if (t < HD) s.u.hp.pool[t] = 0.0f;
  __syncthreads();
  {
    float cs[4];
    #pragma unroll
    for (int nt = 0; nt < 4; ++nt) {
      cs[nt] = ((hr[nt][0] + hr[nt][1]) + (hr[nt][2] + hr[nt][3])) * (1.0f / 64.0f);
      cs[nt] += __shfl_xor(cs[nt], 16, 64);
      cs[nt] += __shfl_xor(cs[nt], 32, 64);
    }
    if (lane < 16) {
      #pragma unroll
      for (int nt = 0; nt < 4; ++nt)
        atomicAdd(&s.u.hp.pool[nt * 16 + lane], cs[nt]);
    }
  }
  __syncthreads();
  if (t < HD) {
    float acc = bp1[t];
    #pragma unroll 8
    for (int k = 0; k < HD; ++k) acc = fmaf(s.u.hp.pool[k], Wp1[k * HD + t], acc);
    s.u.hp.y1[t] = fmaxf(acc, 0.0f);
  }
  __syncthreads();
  if (t < ODIM) {
    float acc = bp2[t];
    #pragma unroll 8
    for (int c = 0; c < HD; ++c) acc = fmaf(s.u.hp.y1[c], Wp2[c * ODIM + t], acc);
    out[eg * ODIM + t] = acc;
  }
}

extern "C" void kernel_launch(void* const* d_in, const int* in_sizes, int n_in,
                              void* d_out, int out_size, void* d_ws, size_t ws_size,
                              hipStream_t stream) {
  const float* x    = (const float*)d_in[0];
  const int*   adj  = (const int*)d_in[1];
  const float* W_in = (const float*)d_in[2];
  const float* b_in = (const float*)d_in[3];
  const float* Wq   = (const float*)d_in[4];
  const float* Wk   = (const float*)d_in[5];
  const float* Wv   = (const float*)d_in[6];
  const float* Wo   = (const float*)d_in[7];
  const float* bo   = (const float*)d_in[8];
  const float* lng  = (const float*)d_in[9];
  const float* lnb  = (const float*)d_in[10];
  const float* Wp1  = (const float*)d_in[11];
  const float* bp1  = (const float*)d_in[12];
  const float* Wp2  = (const float*)d_in[13];
  const float* bp2  = (const float*)d_in[14];
  float* outp = (float*)d_out;
  u16*   wsW  = (u16*)d_ws;   // 12 * 4096 u16 = 98304 B

  hipLaunchKernelGGL(prep_weights, dim3(NW), dim3(256), 0, stream,
                     Wq, Wk, Wv, Wo, wsW);
  hipLaunchKernelGGL(gnn_fused, dim3(BTOT), dim3(NTH), 0, stream,
                     x, adj, W_in, b_in, wsW, bo, lng, lnb,
                     Wp1, bp1, Wp2, bp2, outp);
}